// Round 1
// 106.833 us; speedup vs baseline: 1.0101x; 1.0101x over previous
//
#include <hip/hip_runtime.h>
#include <hip/hip_bf16.h>

typedef short v8s __attribute__((ext_vector_type(8)));
typedef float v4f __attribute__((ext_vector_type(4)));

#define NN 1024
#define MM 32
#define DD 256
#define NMROWS (NN * MM)

__device__ __forceinline__ unsigned short f2bf(float f) {
    unsigned u = __float_as_uint(f);
    unsigned r = (u + 0x7fffu + ((u >> 16) & 1u)) >> 16;
    return (unsigned short)r;
}

__device__ __forceinline__ void gload_lds16(const void* g, void* l) {
    __builtin_amdgcn_global_load_lds(
        (const __attribute__((address_space(1))) void*)g,
        (__attribute__((address_space(3))) void*)l, 16, 0, 0);
}

// Kernel 1: per-speaker centroids (scaled by kappa/M into bf16), e->bf16 copy,
// exact fp32 sigma_own per row. (Diagonal exclusion moved into k_gemm.)
__global__ __launch_bounds__(256) void k_centroid(
    const float* __restrict__ e, const float* __restrict__ wp,
    unsigned short* __restrict__ c_scaled,   // [NN][DD] bf16 bits = bf16(kappa * s / M)
    unsigned short* __restrict__ e_bf,       // [NMROWS][DD] bf16 bits
    float* __restrict__ sig_own)
{
    __shared__ float es[MM][260];    // +4 pad: row stride 260 ≡ 4 mod 32 banks
    __shared__ float s_l[DD];
    const int n = blockIdx.x, t = threadIdx.x;
    const float kappa = wp[0] * 1.44269504088896340736f;
    const float* eb0 = e + (size_t)n * MM * DD;

    // stage 32x256 fp32 -> LDS, and write bf16 copy to global
    for (int r = 0; r < 8; ++r) {
        int id = r * 256 + t;              // 0..2047 float4 chunks
        int m = id >> 6, c4 = (id & 63) << 2;
        float4 v = *reinterpret_cast<const float4*>(eb0 + m * DD + c4);
        *reinterpret_cast<float4*>(&es[m][c4]) = v;
        ushort4 bv;
        bv.x = f2bf(v.x); bv.y = f2bf(v.y); bv.z = f2bf(v.z); bv.w = f2bf(v.w);
        *reinterpret_cast<ushort4*>(e_bf + (size_t)(n * MM + m) * DD + c4) = bv;
    }
    __syncthreads();

    // centroid sum over m for d = t; write scaled bf16 centroid
    {
        float s = 0.f;
        #pragma unroll
        for (int m = 0; m < MM; ++m) s += es[m][t];
        s_l[t] = s;
        c_scaled[n * DD + t] = f2bf(s * (kappa / (float)MM));
    }
    __syncthreads();

    // per-row exact fp32 LOO dot: 8 threads per row
    const int m = t >> 3, j = t & 7;
    float a1 = 0.f, a2 = 0.f;
    #pragma unroll
    for (int ii = 0; ii < 32; ++ii) {
        int d = j + (ii << 3);
        float ev = es[m][d];
        a1 += ev * s_l[d];
        a2 += ev * ev;
    }
    a1 += __shfl_xor(a1, 1, 8); a1 += __shfl_xor(a1, 2, 8); a1 += __shfl_xor(a1, 4, 8);
    a2 += __shfl_xor(a2, 1, 8); a2 += __shfl_xor(a2, 2, 8); a2 += __shfl_xor(a2, 4, 8);
    if (j == 0)
        sig_own[n * MM + m] = kappa * (a1 - a2) * (1.0f / (float)(MM - 1));
}

// Kernel 2: fused sim-GEMM + exp-sum with diagonal exclusion.
// v2 schedule: double-buffered linear LDS, direct global_load_lds (width 16)
// with XOR-preswizzled global source (conflict-free reads, no padding),
// ONE barrier per 64-col tile, setprio around the MFMA cluster.
// LDS slot (col, chunk16B) holds global (col, chunk ^ (col&7)); reads XOR back.
__global__ __launch_bounds__(256, 2) void k_gemm(
    const unsigned short* __restrict__ e_bf,
    const unsigned short* __restrict__ c_scaled,
    float* __restrict__ partS)               // [2][NMROWS]
{
    __shared__ unsigned short lc[2][64 * 256];   // two 32 KB linear buffers
    const int t = threadIdx.x;
    const int wave = t >> 6, lane = t & 63;
    const int r16 = lane & 15, q = lane >> 4;

    // XCD-chunked remap: consecutive work-ids (incl. the colchunk pair of the
    // same 128 rows) land on the same XCD -> e_bf re-read hits that XCD's L2.
    const int wid = ((blockIdx.x & 7) << 6) | (blockIdx.x >> 3);
    const int rowblk = wid >> 1, colchunk = wid & 1;
    const int row0 = rowblk * 128, col0 = colchunk * 512;

    // issue tile 'it' (64 cols x 256 k, 32 KB) into lc[buf]: 8 x 1KB DMA per wave.
    // dest (linear): col = wave*16 + 2j + (lane>>5), chunk = lane&31
    // src  (swizzled): global (colg, (lane&31) ^ (colg&7))
    const int half = lane >> 5, c31 = lane & 31;
    const char* cbytes = (const char*)c_scaled;

    // A fragments: A[m=lane&15][k=(lane>>4)*8+j], register-resident for whole block
    v8s A[2][8];
    {
        // overlap the first tile's DMA with the A-fragment global loads
        #pragma unroll
        for (int j = 0; j < 8; ++j) {
            int colg = col0 + wave * 16 + 2 * j + half;
            const char* src = cbytes + ((size_t)colg << 9) + ((c31 ^ (colg & 7)) << 4);
            gload_lds16(src, &lc[0][(wave * 16 + 2 * j) * 256]);
        }
        #pragma unroll
        for (int rt = 0; rt < 2; ++rt) {
            const unsigned short* ap =
                e_bf + (size_t)(row0 + wave * 32 + rt * 16 + r16) * DD + q * 8;
            #pragma unroll
            for (int kb = 0; kb < 8; ++kb)
                A[rt][kb] = *reinterpret_cast<const v8s*>(ap + kb * 32);
        }
    }

    // speaker id per rt-tile (uniform across the tile's 16 rows)
    const int spk0 = (row0 + wave * 32) >> 5;
    const int spk1 = (row0 + wave * 32 + 16) >> 5;

    __syncthreads();    // drains vmcnt(0): tile 0 resident in lc[0]

    float sums[2][4] = {};
    #pragma unroll
    for (int it = 0; it < 8; ++it) {
        const int cur = it & 1;
        if (it < 7) {   // prefetch next tile into the other buffer under MFMA
            #pragma unroll
            for (int j = 0; j < 8; ++j) {
                int colg = col0 + (it + 1) * 64 + wave * 16 + 2 * j + half;
                const char* src =
                    cbytes + ((size_t)colg << 9) + ((c31 ^ (colg & 7)) << 4);
                gload_lds16(src, &lc[cur ^ 1][(wave * 16 + 2 * j) * 256]);
            }
        }

        const unsigned short* lb = lc[cur];
        v4f acc[2][4] = {};
        __builtin_amdgcn_s_setprio(1);
        #pragma unroll
        for (int kb = 0; kb < 8; ++kb) {
            const int sw = ((((kb << 2) | q) ^ (r16 & 7)) << 3);  // shorts
            v8s b[4];
            #pragma unroll
            for (int ct = 0; ct < 4; ++ct)
                b[ct] = *reinterpret_cast<const v8s*>(
                    &lb[(ct * 16 + r16) * 256 + sw]);
            #pragma unroll
            for (int rt = 0; rt < 2; ++rt)
                #pragma unroll
                for (int ct = 0; ct < 4; ++ct)
                    acc[rt][ct] = __builtin_amdgcn_mfma_f32_16x16x32_bf16(
                        A[rt][kb], b[ct], acc[rt][ct], 0, 0, 0);
        }
        __builtin_amdgcn_s_setprio(0);

        const int ct0 = col0 + it * 64;
        #pragma unroll
        for (int ct = 0; ct < 4; ++ct) {
            const int col = ct0 + ct * 16 + r16;    // D layout: col = lane&15
            const bool skip0 = (col == spk0), skip1 = (col == spk1);
            #pragma unroll
            for (int i = 0; i < 4; ++i) {
                float e0 = __builtin_amdgcn_exp2f(acc[0][ct][i]);
                float e1 = __builtin_amdgcn_exp2f(acc[1][ct][i]);
                sums[0][i] += skip0 ? 0.f : e0;
                sums[1][i] += skip1 ? 0.f : e1;
            }
        }
        if (it < 7) __syncthreads();   // nxt buffer ready; cur safe to overwrite
    }

    // D layout: row = (lane>>4)*4 + reg. Reduce over the 16 col-lanes.
    #pragma unroll
    for (int rt = 0; rt < 2; ++rt)
        #pragma unroll
        for (int i = 0; i < 4; ++i) {
            float v = sums[rt][i];
            v += __shfl_xor(v, 1, 16);
            v += __shfl_xor(v, 2, 16);
            v += __shfl_xor(v, 4, 16);
            v += __shfl_xor(v, 8, 16);
            sums[rt][i] = v;
        }
    if (r16 == 0) {
        #pragma unroll
        for (int rt = 0; rt < 2; ++rt)
            #pragma unroll
            for (int i = 0; i < 4; ++i) {
                int row = row0 + wave * 32 + rt * 16 + q * 4 + i;
                partS[colchunk * NMROWS + row] = sums[rt][i];
            }
    }
}

// Kernel 3: per-row LSE (diagonal already excluded in k2), reduce to scalar loss.
__global__ __launch_bounds__(256) void k_loss(
    const float* __restrict__ partS, const float* __restrict__ sig_own,
    float* __restrict__ out)
{
    const int t = threadIdx.x;
    const int row = blockIdx.x * 256 + t;
    float S  = partS[row] + partS[NMROWS + row];
    float so = sig_own[row];
    float Sp = S + __builtin_amdgcn_exp2f(so);
    float lr = 0.69314718055994530942f * (__builtin_amdgcn_logf(Sp) - so);
    #pragma unroll
    for (int off = 1; off < 64; off <<= 1) lr += __shfl_xor(lr, off, 64);
    __shared__ float ws4[4];
    if ((t & 63) == 0) ws4[t >> 6] = lr;
    __syncthreads();
    if (t == 0) {
        float tot = ws4[0] + ws4[1] + ws4[2] + ws4[3];
        atomicAdd(out, tot * (1.0f / (float)NMROWS));
    }
}

extern "C" void kernel_launch(void* const* d_in, const int* in_sizes, int n_in,
                              void* d_out, int out_size, void* d_ws, size_t ws_size,
                              hipStream_t stream)
{
    const float* e = (const float*)d_in[0];
    const float* w = (const float*)d_in[1];
    char* ws = (char*)d_ws;

    unsigned short* c_scaled = (unsigned short*)ws;                       // 512 KB
    unsigned short* e_bf     = (unsigned short*)(ws + (size_t)(1 << 19)); // 16 MB
    float* sig_own = (float*)(ws + (size_t)(1 << 19) + (size_t)NMROWS * DD * 2);
    float* partS   = sig_own + NMROWS;                                    // [2][NMROWS]
    float* outf = (float*)d_out;

    hipMemsetAsync(d_out, 0, sizeof(float), stream);
    hipLaunchKernelGGL(k_centroid, dim3(NN), dim3(256), 0, stream,
                       e, w, c_scaled, e_bf, sig_own);
    hipLaunchKernelGGL(k_gemm, dim3(512), dim3(256), 0, stream,
                       e_bf, c_scaled, partS);
    hipLaunchKernelGGL(k_loss, dim3(NMROWS / 256), dim3(256), 0, stream,
                       partS, sig_own, outf);
}